// Round 2
// baseline (239.829 us; speedup 1.0000x reference)
//
#include <hip/hip_runtime.h>

#define Bn 128
#define Vn 128000
#define SLICES 8
#define SLICE_LEN 16000      // Vn/SLICES, divisible by 4
#define TPB 256
#define WTPB 512
#define NB1 512              // L1 bins: K>>21 (e<=1 -> bin<=508)
#define NB2 512              // L2 sub-bins: K bits [20:12]
#define CAP 512
#define CAPB 4096            // q4 bin-level candidate cap (expect <~500)
#define FMINV -3.4028234663852886e38f
#define FOUT  -3.3895313892515355e38f

// ---- ws arena (bytes) ----
#define OFF_ROWS   0u
#define OFF_SLICEM 65536u
#define OFF_L1S    81920u
#define OFF_L1C    606208u
#define OFF_L2S    868352u
#define OFF_L2C    3489792u
#define OFF_LCNT   4800512u
#define OFF_LISTS  4804608u
#define OFF_Q4BIG  7426048u                          // fast path only
#define WS_NEED_FAST (OFF_Q4BIG + (size_t)Bn*CAPB*8u)  // ~11.6 MB
#define ZERO_U64   600576u
#define SKIP_LO    8192u
#define SKIP_HI    10240u

// Unnormalized probabilities e = exp2((v-M)*log2e/T) <= 1. All decisions are
// scale-invariant; Z = suffix-scan total, published once as Zd.
struct RowWS {
  double Zd;
  float S2f, t4;
  unsigned thrBits;
  int q4mode, token;
  unsigned v0; int i0; unsigned v2; int i2;
  unsigned cutBin[5];                 // L1 cut bin q0..3 (l2hist), q4 (resolve)
  unsigned CbefB[4]; double SbefB[4]; // bin-level excl suffix (l2hist, sl==0)
  unsigned cutPre[5];                 // sub-level prefix (slow path q4 only)
  unsigned Cbef[5]; double Sbef[5];   // sub-level q0..3 (collect); q4 bin-level (resolve), sub (q4walk slow)
};

// 256-thread suffix-inclusive scan over 512 (s,c) bins; thread t owns 2t,2t+1.
__device__ inline void sufscan512(int tid, double s0, unsigned c0, double s1, unsigned c1,
    double& S0i, unsigned& C0i, double& S1i, unsigned& C1i, double& St,
    double* wT, unsigned* wTc){
  __syncthreads();                       // protect wT reuse + preceding shared init
  int lane = tid & 63, wv = tid >> 6;
  double vS = s0 + s1; unsigned vC = c0 + c1;
  #pragma unroll
  for (int off = 1; off < 64; off <<= 1){
    double tS = __shfl_down(vS, off); unsigned tC = __shfl_down(vC, off);
    if (lane + off < 64){ vS += tS; vC += tC; }
  }
  if (lane == 0){ wT[wv] = vS; wTc[wv] = vC; }
  __syncthreads();
  double add = 0.0; unsigned addc = 0u;
  for (int w = wv + 1; w < 4; ++w){ add += wT[w]; addc += wTc[w]; }
  S0i = vS + add; C0i = vC + addc;
  S1i = S0i - s0; C1i = C0i - c0;
  St = wT[0] + wT[1] + wT[2] + wT[3];
}

// ---- pass 1: fused ws-zero + per-slice max ----
__global__ __launch_bounds__(TPB) void k_max(const float* __restrict__ logits,
    float* sliceM, unsigned long long* wsz){
  {
    size_t i = (size_t)blockIdx.x*TPB + threadIdx.x;
    size_t st = (size_t)gridDim.x*TPB;
    for (; i < ZERO_U64; i += st)
      if (i < SKIP_LO || i >= SKIP_HI) wsz[i] = 0ull;
  }
  __shared__ float sF[TPB/64];
  int blk = blockIdx.x, b = blk >> 3, sl = blk & 7, tid = threadIdx.x;
  const float4* l4 = (const float4*)(logits + (size_t)b*Vn + sl*SLICE_LEN);
  float m = -3.4e38f;
  for (int j = tid; j < SLICE_LEN/4; j += TPB){
    float4 v = l4[j];
    m = fmaxf(m, fmaxf(fmaxf(v.x, v.y), fmaxf(v.z, v.w)));
  }
  #pragma unroll
  for (int o = 32; o; o >>= 1) m = fmaxf(m, __shfl_down(m, o));
  if ((tid & 63) == 0) sF[tid >> 6] = m;
  __syncthreads();
  if (tid == 0){
    float mm = sF[0];
    for (int w = 1; w < TPB/64; ++w) mm = fmaxf(mm, sF[w]);
    sliceM[b*SLICES + sl] = mm;
  }
}

// ---- pass 2: e = exp2((v-M)*c1), cache K, L1 histogram ----
__global__ __launch_bounds__(TPB) void k_l1hist(const float* __restrict__ logits,
    const float* __restrict__ temps, const float* __restrict__ sliceM,
    double* L1S, unsigned* L1C, unsigned* __restrict__ Kc){
  __shared__ double   hS[4*NB1];
  __shared__ unsigned hC[4*NB1];
  __shared__ float sM;
  int blk = blockIdx.x, b = blk >> 3, sl = blk & 7, tid = threadIdx.x;
  int cp = (tid >> 6) & 3;
  for (int i = tid; i < 4*NB1; i += TPB){ hS[i] = 0.0; hC[i] = 0u; }
  float T = temps[b];
  float c1 = 1.4426950408889634f / T;
  if (tid == 0){
    float M = sliceM[b*SLICES];
    for (int s = 1; s < SLICES; ++s) M = fmaxf(M, sliceM[b*SLICES + s]);
    sM = M;
  }
  __syncthreads();
  float M = sM;
  size_t base = (size_t)b*Vn + sl*SLICE_LEN;
  const float4* l4 = (const float4*)(logits + base);
  uint4* K4 = (uint4*)(Kc + base);
  for (int j = tid; j < SLICE_LEN/4; j += TPB){
    float4 v = l4[j];
    uint4 kk;
    float p0 = exp2f((v.x - M)*c1); kk.x = __float_as_uint(p0);
    float p1 = exp2f((v.y - M)*c1); kk.y = __float_as_uint(p1);
    float p2 = exp2f((v.z - M)*c1); kk.z = __float_as_uint(p2);
    float p3 = exp2f((v.w - M)*c1); kk.w = __float_as_uint(p3);
    unsigned b0 = min(kk.x >> 21, NB1-1u), b1 = min(kk.y >> 21, NB1-1u);
    unsigned b2 = min(kk.z >> 21, NB1-1u), b3 = min(kk.w >> 21, NB1-1u);
    unsafeAtomicAdd(&hS[cp*NB1 + b0], (double)p0); atomicAdd(&hC[cp*NB1 + b0], 1u);
    unsafeAtomicAdd(&hS[cp*NB1 + b1], (double)p1); atomicAdd(&hC[cp*NB1 + b1], 1u);
    unsafeAtomicAdd(&hS[cp*NB1 + b2], (double)p2); atomicAdd(&hC[cp*NB1 + b2], 1u);
    unsafeAtomicAdd(&hS[cp*NB1 + b3], (double)p3); atomicAdd(&hC[cp*NB1 + b3], 1u);
    K4[j] = kk;
  }
  __syncthreads();
  for (int bin = tid; bin < NB1; bin += TPB){
    unsigned c = hC[bin] + hC[NB1+bin] + hC[2*NB1+bin] + hC[3*NB1+bin];
    if (c){
      double s = hS[bin] + hS[NB1+bin] + hS[2*NB1+bin] + hS[3*NB1+bin];
      unsafeAtomicAdd(&L1S[(size_t)b*NB1 + bin], s);
      atomicAdd(&L1C[(size_t)b*NB1 + bin], c);
    }
  }
}

// ---- pass 3: embedded L1 walk (redundant per block) + L2 histograms q0..q3 ----
__global__ __launch_bounds__(TPB) void k_l2hist(const unsigned* __restrict__ Kc,
    const double* __restrict__ L1S, const unsigned* __restrict__ L1C,
    RowWS* rows, double* L2S, unsigned* L2C,
    const int* __restrict__ top_ks, const float* __restrict__ top_ps,
    const float* __restrict__ top_ps2, const float* __restrict__ min_ps){
  __shared__ double   hS[4*NB2];
  __shared__ unsigned hC[4*NB2];
  __shared__ double wT[4]; __shared__ unsigned wTc[4];
  __shared__ int mx0, mx1, mx2, mnz;
  __shared__ unsigned sCut[4];
  int blk = blockIdx.x, b = blk >> 3, sl = blk & 7, tid = threadIdx.x;
  RowWS& R = rows[b];
  for (int i = tid; i < 4*NB2; i += TPB){ hS[i] = 0.0; hC[i] = 0u; }
  if (tid == 0){ mx0 = -1; mx1 = -1; mx2 = -1; mnz = NB1; }
  int B0 = 2*tid, B1 = 2*tid+1;
  double s0 = L1S[(size_t)b*NB1 + B0], s1 = L1S[(size_t)b*NB1 + B1];
  unsigned c0 = L1C[(size_t)b*NB1 + B0], c1 = L1C[(size_t)b*NB1 + B1];
  double S0i, S1i, St; unsigned C0i, C1i;
  sufscan512(tid, s0, c0, s1, c1, S0i, C0i, S1i, C1i, St, wT, wTc);
  float minp = min_ps[b];
  unsigned thrBits = __float_as_uint(minp);
  int thrBin = (int)(thrBits >> 21); if (thrBin > NB1-1) thrBin = NB1-1;
  unsigned k = (unsigned)top_ks[b];
  double tZ1 = (double)top_ps[b] * St, tZ2 = (double)top_ps2[b] * St;
  if (c0){ if (C0i >= k) atomicMax(&mx0,B0); if (S0i > tZ1) atomicMax(&mx1,B0); if (S0i > tZ2) atomicMax(&mx2,B0); atomicMin(&mnz,B0); }
  if (c1){ if (C1i >= k) atomicMax(&mx0,B1); if (S1i > tZ1) atomicMax(&mx1,B1); if (S1i > tZ2) atomicMax(&mx2,B1); atomicMin(&mnz,B1); }
  __syncthreads();
  int w0 = mx0;
  int w1 = (mx1 >= 0) ? mx1 : mnz;
  int w2 = (mx2 >= 0) ? mx2 : mnz;
  if (tid == 0){
    sCut[0]=(unsigned)w0; sCut[1]=(unsigned)w1; sCut[2]=(unsigned)w2; sCut[3]=(unsigned)thrBin;
    if (sl == 0){
      R.thrBits = thrBits; R.Zd = St;
      R.cutBin[0]=(unsigned)w0; R.cutBin[1]=(unsigned)w1; R.cutBin[2]=(unsigned)w2; R.cutBin[3]=(unsigned)thrBin;
    }
  }
  if (sl == 0){
    #define PUB(qi, wq) { if (B0==(wq)){ R.CbefB[qi]=C0i-c0; R.SbefB[qi]=S0i-s0; } else if (B1==(wq)){ R.CbefB[qi]=C1i-c1; R.SbefB[qi]=S1i-s1; } }
    PUB(0, w0) PUB(1, w1) PUB(2, w2) PUB(3, thrBin)
    #undef PUB
  }
  __syncthreads();
  unsigned tb0 = sCut[0], tb1 = sCut[1], tb2 = sCut[2], tb3 = sCut[3];
  const uint4* K4 = (const uint4*)(Kc + (size_t)b*Vn + sl*SLICE_LEN);
  for (int j = tid; j < SLICE_LEN/4; j += TPB){
    uint4 kk = K4[j];
    #pragma unroll
    for (int c = 0; c < 4; ++c){
      unsigned K = (c==0)?kk.x:(c==1)?kk.y:(c==2)?kk.z:kk.w;
      unsigned bin = K >> 21, sub = (K >> 12) & (NB2-1);
      double p = (double)__uint_as_float(K);
      if (bin == tb0){ unsafeAtomicAdd(&hS[0*NB2+sub], p); atomicAdd(&hC[0*NB2+sub], 1u); }
      if (bin == tb1){ unsafeAtomicAdd(&hS[1*NB2+sub], p); atomicAdd(&hC[1*NB2+sub], 1u); }
      if (bin == tb2){ unsafeAtomicAdd(&hS[2*NB2+sub], p); atomicAdd(&hC[2*NB2+sub], 1u); }
      if (bin == tb3){ unsafeAtomicAdd(&hS[3*NB2+sub], p); atomicAdd(&hC[3*NB2+sub], 1u); }
    }
  }
  __syncthreads();
  for (int i = tid; i < 4*NB2; i += TPB){
    if (hC[i]){
      unsafeAtomicAdd(&L2S[((size_t)b*5)*NB2 + i], hS[i]);
      atomicAdd(&L2C[((size_t)b*5)*NB2 + i], hC[i]);
    }
  }
}

// ---- pass 4: embedded L2 walks (redundant) + collect boundary candidates ----
__global__ __launch_bounds__(TPB) void k_collect(const unsigned* __restrict__ Kc,
    RowWS* rows, const double* __restrict__ L2S, const unsigned* __restrict__ L2C,
    const int* __restrict__ top_ks, const float* __restrict__ top_ps,
    const float* __restrict__ top_ps2,
    unsigned long long* lists, unsigned* lcnt){
  __shared__ double wT[4]; __shared__ unsigned wTc[4];
  __shared__ int mx, mnz;
  __shared__ unsigned sPre[4];
  int blk = blockIdx.x, b = blk >> 3, sl = blk & 7, tid = threadIdx.x;
  RowWS& R = rows[b];
  unsigned thrBits = R.thrBits; double Zd = R.Zd;
  unsigned k = (unsigned)top_ks[b];
  int B0 = 2*tid, B1 = 2*tid+1;
  for (int q = 0; q < 4; ++q){
    if (tid == 0){ mx = -1; mnz = NB2; }
    size_t hbase = ((size_t)b*5+q)*NB2;
    double s0 = L2S[hbase+B0], s1 = L2S[hbase+B1];
    unsigned c0 = L2C[hbase+B0], c1 = L2C[hbase+B1];
    double S0i, S1i, St; unsigned C0i, C1i;
    sufscan512(tid, s0, c0, s1, c1, S0i, C0i, S1i, C1i, St, wT, wTc);
    unsigned baseC = R.CbefB[q]; double baseS = R.SbefB[q];
    int w;
    if (q == 3){
      w = (int)((thrBits >> 12) & (NB2-1));
    } else if (q == 0){
      if (c0 && baseC + C0i >= k) atomicMax(&mx, B0);
      if (c1 && baseC + C1i >= k) atomicMax(&mx, B1);
      if (c0) atomicMin(&mnz, B0);
      if (c1) atomicMin(&mnz, B1);
      w = 0;
    } else {
      double tau = ((q == 1) ? (double)top_ps[b] : (double)top_ps2[b]) * Zd;
      if (c0 && baseS + S0i > tau) atomicMax(&mx, B0);
      if (c1 && baseS + S1i > tau) atomicMax(&mx, B1);
      if (c0) atomicMin(&mnz, B0);
      if (c1) atomicMin(&mnz, B1);
      w = 0;
    }
    __syncthreads();
    if (q != 3) w = (mx >= 0) ? mx : mnz;
    if (B0 == w || B1 == w){
      bool o = (B0 == w);
      unsigned Cs = baseC + (o ? C0i - c0 : C1i - c1);
      double   Ss = baseS + (o ? S0i - s0 : S1i - s1);
      if (sl == 0){ R.Cbef[q] = Cs; R.Sbef[q] = Ss; }
    }
    if (tid == 0) sPre[q] = (R.cutBin[q] << 9) | (unsigned)w;
    __syncthreads();
  }
  unsigned t0 = sPre[0], t1 = sPre[1], t2 = sPre[2], t3 = sPre[3];
  int base = sl*SLICE_LEN;
  const uint4* K4 = (const uint4*)(Kc + (size_t)b*Vn + base);
  for (int j = tid; j < SLICE_LEN/4; j += TPB){
    uint4 kk = K4[j];
    #pragma unroll
    for (int c = 0; c < 4; ++c){
      unsigned K = (c==0)?kk.x:(c==1)?kk.y:(c==2)?kk.z:kk.w;
      unsigned pre = K >> 12;
      if (pre != t0 && pre != t1 && pre != t2 && pre != t3) continue;
      int i = base + j*4 + c;
      unsigned long long e = (((unsigned long long)(~K)) << 32) | (unsigned)i;
      if (pre == t0){ unsigned pos = atomicAdd(&lcnt[b*8+0], 1u); if (pos < CAP) lists[((size_t)b*5+0)*CAP+pos] = e; }
      if (pre == t1){ unsigned pos = atomicAdd(&lcnt[b*8+1], 1u); if (pos < CAP) lists[((size_t)b*5+1)*CAP+pos] = e; }
      if (pre == t2){ unsigned pos = atomicAdd(&lcnt[b*8+2], 1u); if (pos < CAP) lists[((size_t)b*5+2)*CAP+pos] = e; }
      if (pre == t3){ unsigned pos = atomicAdd(&lcnt[b*8+3], 1u); if (pos < CAP) lists[((size_t)b*5+3)*CAP+pos] = e; }
    }
  }
}

// ---- resolve boundaries (thread 0) + PARALLEL q4 L1 walk ----
__global__ __launch_bounds__(WTPB) void k_resolve(RowWS* rows, const unsigned long long* lists,
    const unsigned* lcnt, const double* L1S, const unsigned* L1C,
    const int* __restrict__ top_ks, const float* __restrict__ top_ps,
    const float* __restrict__ top_ps2, const float* __restrict__ uarr){
  __shared__ double   sS[NB1+1];
  __shared__ unsigned sC[NB1+1];
  __shared__ unsigned long long Ls[4*CAP];
  __shared__ int mx;
  __shared__ double sT4d;
  int b = blockIdx.x, t = threadIdx.x;
  RowWS& R = rows[b];
  int nq[4];
  for (int q = 0; q < 4; ++q){
    int n = (int)lcnt[b*8+q]; if (n > CAP) n = CAP; nq[q] = n;
    for (int j = t; j < n; j += WTPB) Ls[q*CAP+j] = lists[((size_t)b*5+q)*CAP + j];
  }
  if (t == 0){ sS[NB1] = 0.0; sC[NB1] = 0u; mx = -1; }
  unsigned c = L1C[(size_t)b*NB1 + t];
  double   s = L1S[(size_t)b*NB1 + t];
  sS[t] = s; sC[t] = c;
  __syncthreads();
  for (int off = 1; off < NB1; off <<= 1){
    double   vs = sS[t] + ((t+off < NB1) ? sS[t+off] : 0.0);
    unsigned vc = sC[t] + ((t+off < NB1) ? sC[t+off] : 0u);
    __syncthreads();
    sS[t] = vs; sC[t] = vc;
    __syncthreads();
  }
  if (t == 0){
    int k = top_ks[b];
    double Zd = R.Zd;
    double tauP = (double)top_ps[b] * Zd, tauP2 = (double)top_ps2[b] * Zd;
    unsigned vS[4]; int iS[4]; double sk[4];
    for (int q = 0; q < 4; ++q){
      int n = nq[q];
      unsigned long long* L = &Ls[q*CAP];
      for (int i2 = 1; i2 < n; ++i2){
        unsigned long long key = L[i2]; int j = i2-1;
        while (j >= 0 && L[j] > key){ L[j+1] = L[j]; --j; }
        L[j+1] = key;
      }
      double S = R.Sbef[q];
      if (q == 0){
        if (n > 0){
          int mm = k - (int)R.Cbef[0]; if (mm < 1) mm = 1; if (mm > n) mm = n;
          for (int j = 0; j < mm; ++j){ unsigned K = ~(unsigned)(L[j] >> 32); S += (double)__uint_as_float(K); }
          unsigned long long e = L[mm-1];
          vS[0] = ~(unsigned)(e >> 32); iS[0] = (int)(unsigned)(e & 0xFFFFFFFFu); sk[0] = S;
        } else { vS[0] = 0u; iS[0] = 0x7FFFFFFF; sk[0] = S; }
      } else if (q < 3){
        double tau = (q == 1) ? tauP : tauP2;
        int last = -1;
        for (int j = 0; j < n; ++j){
          if (S > tau) break;
          unsigned K = ~(unsigned)(L[j] >> 32);
          S += (double)__uint_as_float(K); last = j;
        }
        if (n > 0){
          int pick = (last < 0) ? 0 : last;
          unsigned long long e = L[pick];
          vS[q] = ~(unsigned)(e >> 32); iS[q] = (int)(unsigned)(e & 0xFFFFFFFFu); sk[q] = S;
        } else { vS[q] = 0u; iS[q] = 0x7FFFFFFF; sk[q] = S; }
      } else {
        unsigned thrB = R.thrBits;
        for (int j = 0; j < n; ++j){
          unsigned K = ~(unsigned)(L[j] >> 32);
          if (K < thrB) break;
          S += (double)__uint_as_float(K);
        }
        vS[3] = thrB; iS[3] = 0x7FFFFFFF; sk[3] = S;
      }
    }
    unsigned v0 = vS[0]; int i0 = iS[0]; double tot = sk[0];
    if (vS[1] > v0 || (vS[1] == v0 && iS[1] < i0)){ v0 = vS[1]; i0 = iS[1]; tot = sk[1]; }
    if (vS[3] > v0 || (vS[3] == v0 && iS[3] < i0)){ v0 = vS[3]; i0 = iS[3]; tot = sk[3]; }
    R.v0 = v0; R.i0 = i0;
    R.v2 = vS[2]; R.i2 = iS[2]; R.S2f = (float)sk[2];
    float t4 = uarr[b] * (float)tot;
    R.t4 = t4;
    sT4d = (double)t4;
  }
  __syncthreads();
  double t4d = sT4d;
  if (c && sS[t] >= t4d) atomicMax(&mx, t);
  __syncthreads();
  int w = mx;
  if (w < 0){
    if (t == 0){ R.q4mode = 2; R.token = R.i0; }
  } else {
    if (t == 0) R.q4mode = 0;
    if (t == w){ R.cutBin[4] = (unsigned)t; R.Cbef[4] = sC[t+1]; R.Sbef[4] = sS[t+1]; }
  }
}

// ================= FAST PATH (ws >= WS_NEED_FAST) =================

// ---- out2 fast: logprob write + bin-level q4 candidate collect ----
__global__ __launch_bounds__(TPB) void k_out2_f(const RowWS* __restrict__ rows,
    unsigned long long* biglist, unsigned* lcnt, float* __restrict__ outLp){
  int blk = blockIdx.x, b = blk >> 3, sl = blk & 7, tid = threadIdx.x;
  unsigned v2 = rows[b].v2; int i2 = rows[b].i2; float S2f = rows[b].S2f;
  float lgS2 = logf(S2f);
  bool doColl = (rows[b].q4mode == 0);
  unsigned tb4 = rows[b].cutBin[4];
  int base = sl*SLICE_LEN;
  float4* O4 = (float4*)(outLp + (size_t)b*Vn + base);
  const uint4* K4 = (const uint4*)O4;   // aliased: read K, write logprob
  for (int j = tid; j < SLICE_LEN/4; j += TPB){
    uint4 kk = K4[j];
    float4 o;
    #pragma unroll
    for (int c = 0; c < 4; ++c){
      unsigned K = (c==0)?kk.x:(c==1)?kk.y:(c==2)?kk.z:kk.w;
      int i = base + j*4 + c;
      if (doColl && (K >> 21) == tb4){
        unsigned pos = atomicAdd(&lcnt[b*8+4], 1u);
        if (pos < CAPB) biglist[(size_t)b*CAPB + pos] = (((unsigned long long)(~K)) << 32) | (unsigned)i;
      }
      float p = __uint_as_float(K);
      float val = (K > v2 || (K == v2 && i <= i2)) ? fmaxf(logf(p) - lgS2, FMINV) : FOUT;
      if (c==0) o.x = val; else if (c==1) o.y = val; else if (c==2) o.z = val; else o.w = val;
    }
    O4[j] = o;
  }
}

// ---- pick fast: build q4 sub-hist from bin list, scan, filter, walk ----
__global__ __launch_bounds__(WTPB) void k_pick2(RowWS* rows, const unsigned long long* biglist,
    const unsigned* lcnt, float* __restrict__ outTok, float* __restrict__ outNtlp){
  __shared__ double   hS[NB2];
  __shared__ unsigned hC[NB2];
  __shared__ double wT[8];
  __shared__ int mx, mnz, mcnt;
  __shared__ double sSbS;
  __shared__ unsigned long long Ls[CAP];
  int b = blockIdx.x, t = threadIdx.x;
  RowWS& R = rows[b];
  int token = -1; unsigned pB = 0u;
  if (R.q4mode == 2){
    if (t) return;
    token = R.token; pB = R.v0;
  } else {
    int n = (int)lcnt[b*8+4]; if (n > CAPB) n = CAPB;
    hS[t] = 0.0; hC[t] = 0u;
    if (t == 0){ mx = -1; mnz = NB2; mcnt = 0; }
    __syncthreads();
    for (int j = t; j < n; j += WTPB){
      unsigned K = ~(unsigned)(biglist[(size_t)b*CAPB + j] >> 32);
      unsigned sub = (K >> 12) & (NB2-1);
      unsafeAtomicAdd(&hS[sub], (double)__uint_as_float(K));
      atomicAdd(&hC[sub], 1u);
    }
    __syncthreads();
    double s = hS[t]; unsigned c = hC[t];
    int lane = t & 63, wv = t >> 6;
    double vS = s;
    #pragma unroll
    for (int off = 1; off < 64; off <<= 1){
      double tS = __shfl_down(vS, off);
      if (lane + off < 64) vS += tS;
    }
    if (lane == 0) wT[wv] = vS;
    __syncthreads();
    double add = 0.0;
    for (int w2 = wv + 1; w2 < 8; ++w2) add += wT[w2];
    double Si = vS + add;                       // incl suffix at sub t
    double baseS = R.Sbef[4], t4d = (double)R.t4;
    if (c){
      if (baseS + Si >= t4d) atomicMax(&mx, t);
      atomicMin(&mnz, t);
    }
    __syncthreads();
    int w = (mx >= 0) ? mx : ((mnz < NB2) ? mnz : -1);
    if (w < 0){
      if (t) return;
      token = R.i0; pB = R.v0;
    } else {
      if (t == w) sSbS = baseS + (Si - s);
      __syncthreads();
      for (int j = t; j < n; j += WTPB){
        unsigned long long e = biglist[(size_t)b*CAPB + j];
        unsigned K = ~(unsigned)(e >> 32);
        if (((K >> 12) & (NB2-1)) == (unsigned)w){
          int p = atomicAdd(&mcnt, 1);
          if (p < CAP) Ls[p] = e;
        }
      }
      __syncthreads();
      if (t) return;
      int m = mcnt; if (m > CAP) m = CAP;
      for (int i2 = 1; i2 < m; ++i2){
        unsigned long long key = Ls[i2]; int j = i2-1;
        while (j >= 0 && Ls[j] > key){ Ls[j+1] = Ls[j]; --j; }
        Ls[j+1] = key;
      }
      double S = sSbS, t4dd = t4d;
      unsigned v0 = R.v0; int i0 = R.i0;
      token = -1; pB = R.v0;
      for (int j = 0; j < m; ++j){
        unsigned K = ~(unsigned)(Ls[j] >> 32);
        int idx = (int)(unsigned)(Ls[j] & 0xFFFFFFFFu);
        bool kept = (K > v0) || (K == v0 && idx <= i0);
        if (!kept){ token = i0; pB = v0; break; }
        S += (double)__uint_as_float(K);
        if (S >= t4dd){ token = idx; pB = K; break; }
      }
      if (token < 0){ token = i0; pB = v0; }
    }
  }
  unsigned v2 = R.v2; int i2 = R.i2;
  bool kept2 = (pB > v2) || (pB == v2 && token <= i2);
  float pt = __uint_as_float(pB);
  float lp = kept2 ? fmaxf(logf(pt) - logf(R.S2f), FMINV) : FOUT;
  outTok[b] = (float)token;
  outNtlp[b] = lp;
}

// ================= SLOW PATH (small ws) =================

__global__ __launch_bounds__(TPB) void k_q4hist(const unsigned* __restrict__ Kc,
    const RowWS* __restrict__ rows, double* L2S, unsigned* L2C){
  __shared__ double   hS[NB2];
  __shared__ unsigned hC[NB2];
  int blk = blockIdx.x, b = blk >> 3, sl = blk & 7, tid = threadIdx.x;
  if (rows[b].q4mode == 2) return;
  for (int i = tid; i < NB2; i += TPB){ hS[i] = 0.0; hC[i] = 0u; }
  unsigned tb = rows[b].cutBin[4];
  __syncthreads();
  const uint4* K4 = (const uint4*)(Kc + (size_t)b*Vn + sl*SLICE_LEN);
  for (int j = tid; j < SLICE_LEN/4; j += TPB){
    uint4 kk = K4[j];
    #pragma unroll
    for (int c = 0; c < 4; ++c){
      unsigned K = (c==0)?kk.x:(c==1)?kk.y:(c==2)?kk.z:kk.w;
      if ((K >> 21) == tb){
        unsigned sub = (K >> 12) & (NB2-1);
        unsafeAtomicAdd(&hS[sub], (double)__uint_as_float(K)); atomicAdd(&hC[sub], 1u);
      }
    }
  }
  __syncthreads();
  for (int i = tid; i < NB2; i += TPB){
    if (hC[i]){
      unsafeAtomicAdd(&L2S[((size_t)b*5 + 4)*NB2 + i], hS[i]);
      atomicAdd(&L2C[((size_t)b*5 + 4)*NB2 + i], hC[i]);
    }
  }
}

__global__ __launch_bounds__(WTPB) void k_q4walk(RowWS* rows, const double* L2S, const unsigned* L2C){
  __shared__ double   sS[NB2+1];
  __shared__ unsigned sC[NB2+1];
  __shared__ int mx, mnz;
  __shared__ unsigned snapC, snapCut;
  __shared__ double snapS, snapT4;
  int b = blockIdx.x, t = threadIdx.x;
  RowWS& R = rows[b];
  if (R.q4mode == 2) return;
  if (t == 0){
    sS[NB2] = 0.0; sC[NB2] = 0u; mx = -1; mnz = NB2;
    snapC = R.Cbef[4]; snapS = R.Sbef[4]; snapCut = R.cutBin[4]; snapT4 = (double)R.t4;
  }
  unsigned c = L2C[((size_t)b*5+4)*NB2 + t];
  double   s = L2S[((size_t)b*5+4)*NB2 + t];
  sS[t] = s; sC[t] = c;
  __syncthreads();
  for (int off = 1; off < NB2; off <<= 1){
    double   vs = sS[t] + ((t+off < NB2) ? sS[t+off] : 0.0);
    unsigned vc = sC[t] + ((t+off < NB2) ? sC[t+off] : 0u);
    __syncthreads();
    sS[t] = vs; sC[t] = vc;
    __syncthreads();
  }
  double baseS = snapS, t4d = snapT4;
  if (c){
    if (baseS + sS[t] >= t4d) atomicMax(&mx, t);
    atomicMin(&mnz, t);
  }
  __syncthreads();
  int w = (mx >= 0) ? mx : ((mnz < NB2) ? mnz : -1);
  if (w < 0){
    if (t == 0){ R.q4mode = 2; R.token = R.i0; }
  } else if (t == w){
    R.cutPre[4] = (snapCut << 9) | (unsigned)t;
    R.Cbef[4] = snapC + sC[t+1];
    R.Sbef[4] = snapS + sS[t+1];
  }
}

__global__ __launch_bounds__(TPB) void k_out2_s(const RowWS* __restrict__ rows,
    unsigned long long* lists, unsigned* lcnt, float* __restrict__ outLp){
  int blk = blockIdx.x, b = blk >> 3, sl = blk & 7, tid = threadIdx.x;
  unsigned v2 = rows[b].v2; int i2 = rows[b].i2; float S2f = rows[b].S2f;
  float lgS2 = logf(S2f);
  bool doColl = (rows[b].q4mode == 0);
  unsigned t4p = rows[b].cutPre[4];
  int base = sl*SLICE_LEN;
  float4* O4 = (float4*)(outLp + (size_t)b*Vn + base);
  const uint4* K4 = (const uint4*)O4;
  for (int j = tid; j < SLICE_LEN/4; j += TPB){
    uint4 kk = K4[j];
    float4 o;
    #pragma unroll
    for (int c = 0; c < 4; ++c){
      unsigned K = (c==0)?kk.x:(c==1)?kk.y:(c==2)?kk.z:kk.w;
      int i = base + j*4 + c;
      if (doColl && (K >> 12) == t4p){
        unsigned pos = atomicAdd(&lcnt[b*8+4], 1u);
        if (pos < CAP) lists[((size_t)b*5+4)*CAP + pos] = (((unsigned long long)(~K)) << 32) | (unsigned)i;
      }
      float p = __uint_as_float(K);
      float val = (K > v2 || (K == v2 && i <= i2)) ? fmaxf(logf(p) - lgS2, FMINV) : FOUT;
      if (c==0) o.x = val; else if (c==1) o.y = val; else if (c==2) o.z = val; else o.w = val;
    }
    O4[j] = o;
  }
}

__global__ void k_pick(RowWS* rows, const unsigned long long* lists, const unsigned* lcnt,
                       float* __restrict__ outTok, float* __restrict__ outNtlp){
  __shared__ unsigned long long Ls[CAP];
  int b = blockIdx.x, tid = threadIdx.x;
  RowWS& R = rows[b];
  int n = (int)lcnt[b*8+4]; if (n > CAP) n = CAP;
  if (R.q4mode != 2)
    for (int j = tid; j < n; j += 64) Ls[j] = lists[((size_t)b*5+4)*CAP + j];
  __syncthreads();
  if (tid) return;
  int token; unsigned pB;
  if (R.q4mode == 2){ token = R.token; pB = R.v0; }
  else {
    for (int i2 = 1; i2 < n; ++i2){
      unsigned long long key = Ls[i2]; int j = i2-1;
      while (j >= 0 && Ls[j] > key){ Ls[j+1] = Ls[j]; --j; }
      Ls[j+1] = key;
    }
    double S = R.Sbef[4], t4d = (double)R.t4;
    unsigned v0 = R.v0; int i0 = R.i0;
    token = -1; pB = R.v0;
    for (int j = 0; j < n; ++j){
      unsigned K = ~(unsigned)(Ls[j] >> 32);
      int idx = (int)(unsigned)(Ls[j] & 0xFFFFFFFFu);
      bool kept = (K > v0) || (K == v0 && idx <= i0);
      if (!kept){ token = i0; pB = v0; break; }
      S += (double)__uint_as_float(K);
      if (S >= t4d){ token = idx; pB = K; break; }
    }
    if (token < 0){ token = i0; pB = v0; }
  }
  unsigned v2 = R.v2; int i2 = R.i2;
  bool kept2 = (pB > v2) || (pB == v2 && token <= i2);
  float pt = __uint_as_float(pB);
  float lp = kept2 ? fmaxf(logf(pt) - logf(R.S2f), FMINV) : FOUT;
  outTok[b] = (float)token;
  outNtlp[b] = lp;
}

extern "C" void kernel_launch(void* const* d_in, const int* in_sizes, int n_in,
                              void* d_out, int out_size, void* d_ws, size_t ws_size,
                              hipStream_t stream)
{
  const float* logits  = (const float*)d_in[0];
  const float* temps   = (const float*)d_in[1];
  const int*   top_ks  = (const int*)d_in[2];
  const float* top_ps  = (const float*)d_in[3];
  const float* top_ps2 = (const float*)d_in[4];
  const float* min_ps  = (const float*)d_in[5];
  const float* uarr    = (const float*)d_in[6];

  char* ws = (char*)d_ws;
  RowWS*    rows   = (RowWS*)(ws + OFF_ROWS);
  float*    sliceM = (float*)(ws + OFF_SLICEM);
  double*   L1S    = (double*)(ws + OFF_L1S);
  unsigned* L1C    = (unsigned*)(ws + OFF_L1C);
  double*   L2S    = (double*)(ws + OFF_L2S);
  unsigned* L2C    = (unsigned*)(ws + OFF_L2C);
  unsigned* lcnt   = (unsigned*)(ws + OFF_LCNT);
  unsigned long long* lists  = (unsigned long long*)(ws + OFF_LISTS);
  unsigned long long* q4big  = (unsigned long long*)(ws + OFF_Q4BIG);

  float* outTok  = (float*)d_out;
  float* outLp   = outTok + Bn;
  float* outNtlp = outLp + (size_t)Bn * Vn;
  unsigned* Kc   = (unsigned*)outLp;

  const int G = Bn * SLICES;
  k_max     <<<G,  TPB,  0, stream>>>(logits, sliceM, (unsigned long long*)ws);
  k_l1hist  <<<G,  TPB,  0, stream>>>(logits, temps, sliceM, L1S, L1C, Kc);
  k_l2hist  <<<G,  TPB,  0, stream>>>(Kc, L1S, L1C, rows, L2S, L2C, top_ks, top_ps, top_ps2, min_ps);
  k_collect <<<G,  TPB,  0, stream>>>(Kc, rows, L2S, L2C, top_ks, top_ps, top_ps2, lists, lcnt);
  k_resolve <<<Bn, WTPB, 0, stream>>>(rows, lists, lcnt, L1S, L1C, top_ks, top_ps, top_ps2, uarr);
  if (ws_size >= WS_NEED_FAST){
    k_out2_f <<<G,  TPB,  0, stream>>>(rows, q4big, lcnt, outLp);
    k_pick2  <<<Bn, WTPB, 0, stream>>>(rows, q4big, lcnt, outTok, outNtlp);
  } else {
    k_q4hist <<<G,  TPB,  0, stream>>>(Kc, rows, L2S, L2C);
    k_q4walk <<<Bn, WTPB, 0, stream>>>(rows, L2S, L2C);
    k_out2_s <<<G,  TPB,  0, stream>>>(rows, lists, lcnt, outLp);
    k_pick   <<<Bn, 64,   0, stream>>>(rows, lists, lcnt, outTok, outNtlp);
  }
}